// Round 1
// baseline (412.993 us; speedup 1.0000x reference)
//
#include <hip/hip_runtime.h>

// BlockLinearLayer: out[r, n*8+j] = sum_k x[r, n*32+k] * W[n,j,k] + b[n*8+j]
// x: [65536, 4096] f32, W: [128, 8, 32] f32, b: [1024] f32, out: [65536, 1024] f32
//
// Memory-bound (3.2 FLOP/byte). Strategy:
//  - n (block index) is wave-uniform (from blockIdx.x) -> W/b reads become
//    s_load + SGPR-operand v_fma (scalar cache broadcast, no LDS needed).
//  - each thread owns one row x one n-PAIR: reads 256 contiguous B of x,
//    writes 64 contiguous B of out (full cache line -> exact WRITE_SIZE).

#define INPUT_SIZE  4096
#define OUTPUT_SIZE 1024
#define ROWS_PER_BLOCK 256

__global__ __launch_bounds__(256, 4)
void blocklinear_kernel(const float* __restrict__ x,
                        const float* __restrict__ W,
                        const float* __restrict__ b,
                        float* __restrict__ out)
{
    const int row   = blockIdx.y * ROWS_PER_BLOCK + threadIdx.x;
    const int n0    = blockIdx.x * 2;          // first of the two 32-blocks

    // ---- load 64 contiguous x floats for this row (16x float4) ----
    const float* xrow = x + (size_t)row * INPUT_SIZE + (size_t)n0 * 32;
    float xv[64];
#pragma unroll
    for (int i = 0; i < 16; ++i) {
        float4 v = reinterpret_cast<const float4*>(xrow)[i];
        xv[4*i+0] = v.x; xv[4*i+1] = v.y; xv[4*i+2] = v.z; xv[4*i+3] = v.w;
    }

    // ---- compute 16 outputs; W/b indices are wave-uniform -> s_load ----
    float acc[16];
#pragma unroll
    for (int h = 0; h < 2; ++h) {
        const float* Wn = W + (size_t)(n0 + h) * (8 * 32);
#pragma unroll
        for (int j = 0; j < 8; ++j) {
            float s = b[(n0 + h) * 8 + j];
#pragma unroll
            for (int k = 0; k < 32; ++k)
                s = fmaf(Wn[j * 32 + k], xv[h * 32 + k], s);
            acc[h * 8 + j] = s;
        }
    }

    // ---- store 16 contiguous floats (64 B = full line) ----
    float* orow = out + (size_t)row * OUTPUT_SIZE + (size_t)n0 * 8;
#pragma unroll
    for (int i = 0; i < 4; ++i) {
        reinterpret_cast<float4*>(orow)[i] =
            make_float4(acc[4*i+0], acc[4*i+1], acc[4*i+2], acc[4*i+3]);
    }
}

extern "C" void kernel_launch(void* const* d_in, const int* in_sizes, int n_in,
                              void* d_out, int out_size, void* d_ws, size_t ws_size,
                              hipStream_t stream)
{
    const float* x = (const float*)d_in[0];
    const float* W = (const float*)d_in[1];
    const float* b = (const float*)d_in[2];
    float* out = (float*)d_out;

    const int rows = in_sizes[0] / INPUT_SIZE;          // 65536
    dim3 grid(64 /* n-pairs */, rows / ROWS_PER_BLOCK); // (64, 256)
    dim3 block(ROWS_PER_BLOCK);
    hipLaunchKernelGGL(blocklinear_kernel, grid, block, 0, stream, x, W, b, out);
}

// Round 2
// 242.415 us; speedup vs baseline: 1.7037x; 1.7037x over previous
//
#include <hip/hip_runtime.h>

// BlockLinearLayer: out[r, n*8+j] = sum_k x[r, n*32+k] * W[n,j,k] + b[n*8+j]
// x: [65536, 4096] f32, W: [128, 8, 32] f32, b: [1024] f32, out: [65536, 1024] f32
//
// Memory-bound (3.2 FLOP/byte; floor ~210 us at 6.4 TB/s streaming).
// R1 at 413 us used 16KB-strided lane addressing (reads) and 16B partial-line
// stores (writes). This version stages through LDS so that EVERY global
// instruction is a contiguous full-line run:
//   reads : 1 KB/wave-instr = 2 rows x 512 B contiguous
//   writes: 1 KB/wave-instr = 8 rows x 128 B contiguous (full 64B lines)
// W/bias indices are wave-uniform (readfirstlane) -> s_load broadcast.
// LDS row strides 132/36 dwords (== 4 mod 32) -> disjoint-bank-group,
// conflict-free-optimal ds_read_b128/ds_write_b128.

#define IN_COLS   4096
#define OUT_COLS  1024
#define TR        64        // rows per tile
#define TCF       128       // x cols per tile (4 n-blocks of 32)
#define X_STRIDE  132       // dwords per LDS x row (128 + 4 pad)
#define O_STRIDE  36        // dwords per LDS out row (32 + 4 pad)

__global__ __launch_bounds__(256, 4)
void blocklinear_kernel(const float* __restrict__ x,
                        const float* __restrict__ W,
                        const float* __restrict__ bias,
                        float* __restrict__ out)
{
    __shared__ float lds[TR * X_STRIDE];   // 33792 B; out region reuses it
    const int t     = threadIdx.x;
    const int r0    = blockIdx.y * TR;
    const int chunk = blockIdx.x;          // 0..31 (4 n-blocks each)
    const int c0    = chunk * TCF;         // x col base (floats)

    // ---- stage x tile: 8 iters x 4KB; thread t -> row it*8 + t/32, f4 col t%32
    {
        const int f4   = t & 31;
        const int rsub = t >> 5;           // 0..7
#pragma unroll
        for (int it = 0; it < 8; ++it) {
            const int row = it * 8 + rsub;
            const float4 v = reinterpret_cast<const float4*>(
                x + (size_t)(r0 + row) * IN_COLS + c0)[f4];
            float* d = &lds[row * X_STRIDE + f4 * 4];
            d[0] = v.x; d[1] = v.y; d[2] = v.z; d[3] = v.w;
        }
    }
    __syncthreads();

    // ---- compute: wave w owns n-block chunk*4+w, lane l owns row l
    const int w = __builtin_amdgcn_readfirstlane(t >> 6);  // 0..3, wave-uniform
    const int l = t & 63;                                   // row in tile
    const int n = chunk * 4 + w;                            // global 32-block

    float xv[32];
    {
        const float* src = &lds[l * X_STRIDE + w * 32];
#pragma unroll
        for (int q = 0; q < 8; ++q) {
            const float4 v = reinterpret_cast<const float4*>(src)[q];
            xv[4*q+0] = v.x; xv[4*q+1] = v.y; xv[4*q+2] = v.z; xv[4*q+3] = v.w;
        }
    }

    const float* Wn = W + (size_t)n * 256;   // [8][32] for this block
    float acc[8];
#pragma unroll
    for (int j = 0; j < 8; ++j) {
        float s = bias[n * 8 + j];
#pragma unroll
        for (int k = 0; k < 32; ++k)
            s = fmaf(Wn[j * 32 + k], xv[k], s);
        acc[j] = s;
    }
    __syncthreads();   // all x reads done before overwriting LDS with out

    // ---- stage acc to LDS out region [row][O_STRIDE]
    {
        float* d = &lds[l * O_STRIDE + w * 8];
        reinterpret_cast<float4*>(d)[0] = make_float4(acc[0], acc[1], acc[2], acc[3]);
        reinterpret_cast<float4*>(d)[1] = make_float4(acc[4], acc[5], acc[6], acc[7]);
    }
    __syncthreads();

    // ---- cooperative store: 2 iters x 4KB; thread -> row m*32 + t/8, f4 t%8
    {
        const int f4   = t & 7;
        const int rsub = t >> 3;           // 0..31
        const int oc0  = chunk * 32;       // out col base (floats)
#pragma unroll
        for (int m = 0; m < 2; ++m) {
            const int row = m * 32 + rsub;
            const float4 v = *reinterpret_cast<const float4*>(
                &lds[row * O_STRIDE + f4 * 4]);
            reinterpret_cast<float4*>(
                out + (size_t)(r0 + row) * OUT_COLS + oc0)[f4] = v;
        }
    }
}

extern "C" void kernel_launch(void* const* d_in, const int* in_sizes, int n_in,
                              void* d_out, int out_size, void* d_ws, size_t ws_size,
                              hipStream_t stream)
{
    const float* x = (const float*)d_in[0];
    const float* W = (const float*)d_in[1];
    const float* b = (const float*)d_in[2];
    float* out = (float*)d_out;

    const int rows = in_sizes[0] / IN_COLS;            // 65536
    dim3 grid(IN_COLS / TCF, rows / TR);               // (32, 1024)
    dim3 block(256);
    hipLaunchKernelGGL(blocklinear_kernel, grid, block, 0, stream, x, W, b, out);
}